// Round 15
// baseline (895.987 us; speedup 1.0000x reference)
//
#include <hip/hip_runtime.h>

typedef unsigned int u32;

#define NTOK 131072
#define DIMS 1024
#define NT   256

using bf16x8 = __attribute__((ext_vector_type(8))) short;
using f32x4  = __attribute__((ext_vector_type(4))) float;

// d_ws layout:
//   [0, 1MB)        Bf : bf16[2][32][64][16][8]; slice (p,ks) = 16KB;
//                   within slice: L*128 + slot*8 shorts, slot = n ^ (L&15)
//   [1MB, +1KB)     Sv : float[256]   per-tile nonzero count (slow path)
//   [1MB+1KB, ..)   flags : int[256]  per-tile "sig has exact zero" flag
#define BF_OFF   0
#define SV_OFF   (1 << 20)
#define FLAG_OFF ((1 << 20) + 1024)

// dist = Su + Sv - dot(a,b) - dot(u,v)  [R13-verified, exact]
// if sig has NO exact zeros: dist = 1024 - dot(a,b) exactly (any x).
__device__ __forceinline__ short sgnbf(float v) {
    return v > 0.f ? (short)0x3F80 : (v < 0.f ? (short)0xBF80 : (short)0);
}
__device__ __forceinline__ short absbf(float v) {
    return v != 0.f ? (short)0x3F80 : (short)0;
}

// ---------------------------------------------------------------------------
// Kernel A: B-fragments (bf16 sign/abs planes) in MFMA layout, slot-swizzled.
// (unchanged from R14 — bit-exact verified)
// ---------------------------------------------------------------------------
__global__ void sig_kernel(const float* __restrict__ base,
                           const float* __restrict__ deltas,
                           short* __restrict__ Bf,
                           float* __restrict__ Sv,
                           int* __restrict__ flags)
{
    const int t  = blockIdx.x;
    const int l  = threadIdx.x;
    const int ks = l >> 1;
    int nz = 0, zany = 0;
    #pragma unroll
    for (int gh = 0; gh < 2; ++gh) {
        const int g = (l & 1) * 2 + gh;
        bf16x8 a8, u8;
        #pragma unroll
        for (int j = 0; j < 8; ++j) {
            const int d  = ks * 32 + g * 8 + j;
            const float b  = base[d];
            const float dl = (t > 0) ? deltas[(size_t)(t - 1) * DIMS + d] : 0.f;
            const float s  = (dl != 0.f) ? dl : b;
            a8[j] = sgnbf(s);
            u8[j] = absbf(s);
            nz   += (s != 0.f) ? 1 : 0;
            zany |= (s == 0.f) ? 1 : 0;
        }
        const int L    = g * 16 + (t & 15);
        const int n    = t >> 4;
        const int slot = n ^ (t & 15);
        const size_t off = (size_t)L * 128 + slot * 8;
        *(bf16x8*)(Bf + (((size_t)0 * 32 + ks) << 13) + off) = a8;
        *(bf16x8*)(Bf + (((size_t)1 * 32 + ks) << 13) + off) = u8;
    }
    #pragma unroll
    for (int off = 1; off < 64; off <<= 1) nz += __shfl_xor(nz, off);
    const bool za = __any(zany != 0);
    if (l == 0) { Sv[t] = (float)nz; flags[t] = za ? 1 : 0; }
}

// ---------------------------------------------------------------------------
// Kernel B: MFMA dist. 256 thr = 4 waves; block = 128 tokens x 256 tiles.
// Per ks: B slice staged via global_load_lds DMA (R15: no reg round-trip, no
// ds_write/ds_read alias serialization), x prefetched 1 ahead, 16 ds_read +
// 32 MFMA (setprio-wrapped). LDS = 2 x 16KB double buffer only (32 KB) ->
// 3 blocks/CU. Slow path (sig has exact zero, ~never): SECOND full plane
// pass through the same double buffer, accumulating into the same acc
// (identical math to R14's fused 2-plane loop).
// ---------------------------------------------------------------------------
__global__ __launch_bounds__(256, 3)
void dist_kernel(const float* __restrict__ x,
                 const short* __restrict__ Bf,
                 const float* __restrict__ Sv,
                 const int* __restrict__ flags,
                 float* __restrict__ idx_out,
                 float* __restrict__ dist_out)
{
    __shared__ short lds[2][8192];   // 32 KB: [buf][16KB slice]

    const int lane = threadIdx.x & 63;
    const int w    = threadIdx.x >> 6;
    const int tok0 = blockIdx.x * 128 + w * 32;
    const int mrow = lane & 15;
    const int g    = lane >> 4;

    const int ff = flags[lane] | flags[64 + lane] | flags[128 + lane] | flags[192 + lane];
    const bool sigz = __any(ff != 0);

    const float* __restrict__ xr0 = x + (size_t)(tok0 + mrow) * DIMS + g * 8;
    const float* __restrict__ xr1 = x + (size_t)(tok0 + 16 + mrow) * DIMS + g * 8;

    f32x4 acc0[16], acc1[16];
    #pragma unroll
    for (int n = 0; n < 16; ++n) {
        acc0[n] = (f32x4){0.f, 0.f, 0.f, 0.f};
        acc1[n] = (f32x4){0.f, 0.f, 0.f, 0.f};
    }

    // async DMA stage: wave w copies its 4KB quarter of slice (p,ks)
    auto STAGE = [&](int b, int p, int kss) {
        const short* src = Bf + (((size_t)p * 32 + kss) << 13) + w * 2048 + lane * 8;
        short* dst = &lds[b][w * 2048];
        #pragma unroll
        for (int i = 0; i < 4; ++i) {
            __builtin_amdgcn_global_load_lds(
                (const __attribute__((address_space(1))) u32*)(src + i * 512),
                (__attribute__((address_space(3))) u32*)(dst + i * 512),
                16, 0, 0);
        }
    };

    int nz0 = 0, nz1 = 0;
    const int nplanes = sigz ? 2 : 1;

    for (int p = 0; p < nplanes; ++p) {
        STAGE(0, p, 0);
        float4 xv00 = *(const float4*)(xr0);
        float4 xv01 = *(const float4*)(xr0 + 4);
        float4 xv10 = *(const float4*)(xr1);
        float4 xv11 = *(const float4*)(xr1 + 4);

        for (int ks = 0; ks < 32; ++ks) {
            __syncthreads();   // slice (p,ks) DMA + x(ks) loads complete

            float4 nx00, nx01, nx10, nx11;
            if (ks < 31) {
                STAGE((ks + 1) & 1, p, ks + 1);
                nx00 = *(const float4*)(xr0 + (ks + 1) * 32);
                nx01 = *(const float4*)(xr0 + (ks + 1) * 32 + 4);
                nx10 = *(const float4*)(xr1 + (ks + 1) * 32);
                nx11 = *(const float4*)(xr1 + (ks + 1) * 32 + 4);
            }

            bf16x8 f0, f1;
            if (p == 0) {
                f0[0]=sgnbf(xv00.x); f0[1]=sgnbf(xv00.y); f0[2]=sgnbf(xv00.z); f0[3]=sgnbf(xv00.w);
                f0[4]=sgnbf(xv01.x); f0[5]=sgnbf(xv01.y); f0[6]=sgnbf(xv01.z); f0[7]=sgnbf(xv01.w);
                f1[0]=sgnbf(xv10.x); f1[1]=sgnbf(xv10.y); f1[2]=sgnbf(xv10.z); f1[3]=sgnbf(xv10.w);
                f1[4]=sgnbf(xv11.x); f1[5]=sgnbf(xv11.y); f1[6]=sgnbf(xv11.z); f1[7]=sgnbf(xv11.w);
            } else {
                f0[0]=absbf(xv00.x); f0[1]=absbf(xv00.y); f0[2]=absbf(xv00.z); f0[3]=absbf(xv00.w);
                f0[4]=absbf(xv01.x); f0[5]=absbf(xv01.y); f0[6]=absbf(xv01.z); f0[7]=absbf(xv01.w);
                f1[0]=absbf(xv10.x); f1[1]=absbf(xv10.y); f1[2]=absbf(xv10.z); f1[3]=absbf(xv10.w);
                f1[4]=absbf(xv11.x); f1[5]=absbf(xv11.y); f1[6]=absbf(xv11.z); f1[7]=absbf(xv11.w);
                nz0 += (xv00.x!=0.f)+(xv00.y!=0.f)+(xv00.z!=0.f)+(xv00.w!=0.f)
                     + (xv01.x!=0.f)+(xv01.y!=0.f)+(xv01.z!=0.f)+(xv01.w!=0.f);
                nz1 += (xv10.x!=0.f)+(xv10.y!=0.f)+(xv10.z!=0.f)+(xv10.w!=0.f)
                     + (xv11.x!=0.f)+(xv11.y!=0.f)+(xv11.z!=0.f)+(xv11.w!=0.f);
            }

            const short* sa = &lds[ks & 1][0];
            __builtin_amdgcn_s_setprio(1);
            #pragma unroll
            for (int n = 0; n < 16; ++n) {
                const bf16x8 ba = *(const bf16x8*)(sa + lane * 128 + ((n ^ mrow) & 15) * 8);
                acc0[n] = __builtin_amdgcn_mfma_f32_16x16x32_bf16(f0, ba, acc0[n], 0, 0, 0);
                acc1[n] = __builtin_amdgcn_mfma_f32_16x16x32_bf16(f1, ba, acc1[n], 0, 0, 0);
            }
            __builtin_amdgcn_s_setprio(0);

            xv00 = nx00; xv01 = nx01; xv10 = nx10; xv11 = nx11;
        }
        __syncthreads();   // all reads of both buffers done before next plane restages
    }

    // ---- epilogue (R14-verified) ----
    float su0r[4], su1r[4];
    if (sigz) {
        nz0 += __shfl_xor(nz0, 16); nz0 += __shfl_xor(nz0, 32);
        nz1 += __shfl_xor(nz1, 16); nz1 += __shfl_xor(nz1, 32);
        const float s0 = (float)nz0, s1 = (float)nz1;
        #pragma unroll
        for (int r = 0; r < 4; ++r) {
            su0r[r] = __shfl(s0, g * 4 + r);
            su1r[r] = __shfl(s1, g * 4 + r);
        }
    }

    int key0[4] = {0x7fffffff,0x7fffffff,0x7fffffff,0x7fffffff};
    int key1[4] = {0x7fffffff,0x7fffffff,0x7fffffff,0x7fffffff};
    #pragma unroll
    for (int n = 0; n < 16; ++n) {
        const int tile = n * 16 + mrow;
        const float svv = sigz ? Sv[tile] : 0.f;
        #pragma unroll
        for (int r = 0; r < 4; ++r) {
            const float dv0 = sigz ? (su0r[r] + svv - acc0[n][r]) : (1024.f - acc0[n][r]);
            const float dv1 = sigz ? (su1r[r] + svv - acc1[n][r]) : (1024.f - acc1[n][r]);
            dist_out[(size_t)(tok0 + g * 4 + r) * NT + tile]      = dv0;
            dist_out[(size_t)(tok0 + 16 + g * 4 + r) * NT + tile] = dv1;
            key0[r] = min(key0[r], ((int)dv0 << 8) | tile);
            key1[r] = min(key1[r], ((int)dv1 << 8) | tile);
        }
    }
    #pragma unroll
    for (int off = 1; off < 16; off <<= 1) {
        #pragma unroll
        for (int r = 0; r < 4; ++r) {
            key0[r] = min(key0[r], __shfl_xor(key0[r], off));
            key1[r] = min(key1[r], __shfl_xor(key1[r], off));
        }
    }
    if (mrow == 0) {
        #pragma unroll
        for (int r = 0; r < 4; ++r) {
            idx_out[tok0 + g * 4 + r]      = (float)(key0[r] & 255);
            idx_out[tok0 + 16 + g * 4 + r] = (float)(key1[r] & 255);
        }
    }
}

extern "C" void kernel_launch(void* const* d_in, const int* in_sizes, int n_in,
                              void* d_out, int out_size, void* d_ws, size_t ws_size,
                              hipStream_t stream)
{
    const float* x      = (const float*)d_in[0];
    const float* base   = (const float*)d_in[1];
    const float* deltas = (const float*)d_in[2];

    short* Bf  = (short*)((char*)d_ws + BF_OFF);
    float* Sv  = (float*)((char*)d_ws + SV_OFF);
    int* flags = (int*)((char*)d_ws + FLAG_OFF);

    float* idx_out  = (float*)d_out;                 // N floats (tile indices)
    float* dist_out = idx_out + NTOK;                // N*T floats

    sig_kernel<<<NT, 64, 0, stream>>>(base, deltas, Bf, Sv, flags);
    dist_kernel<<<NTOK / 128, 256, 0, stream>>>(x, Bf, Sv, flags, idx_out, dist_out);
}

// Round 16
// 195.499 us; speedup vs baseline: 4.5831x; 4.5831x over previous
//
#include <hip/hip_runtime.h>

typedef unsigned int u32;

#define NTOK 131072
#define DIMS 1024
#define NT   256

using bf16x8 = __attribute__((ext_vector_type(8))) short;
using f32x4  = __attribute__((ext_vector_type(4))) float;

// d_ws layout:
//   [0, 1MB)        Bf : bf16[2][32][64][16][8]; slice (p,ks) = 16KB;
//                   within slice: L*128 + slot*8 shorts, slot = n ^ (L&15)
//   [1MB, +1KB)     Sv : float[256]   per-tile nonzero count (slow path)
//   [1MB+1KB, ..)   flags : int[256]  per-tile "sig has exact zero" flag
#define BF_OFF   0
#define SV_OFF   (1 << 20)
#define FLAG_OFF ((1 << 20) + 1024)

// dist = Su + Sv - dot(a,b) - dot(u,v)  [R13-verified, exact]
// if sig has NO exact zeros: dist = 1024 - dot(a,b) exactly (any x).
__device__ __forceinline__ short sgnbf(float v) {
    return v > 0.f ? (short)0x3F80 : (v < 0.f ? (short)0xBF80 : (short)0);
}
__device__ __forceinline__ short absbf(float v) {
    return v != 0.f ? (short)0x3F80 : (short)0;
}

// ---------------------------------------------------------------------------
// Kernel A: B-fragments (bf16 sign/abs planes) in MFMA layout, slot-swizzled.
// (unchanged since R14 — bit-exact verified)
// ---------------------------------------------------------------------------
__global__ void sig_kernel(const float* __restrict__ base,
                           const float* __restrict__ deltas,
                           short* __restrict__ Bf,
                           float* __restrict__ Sv,
                           int* __restrict__ flags)
{
    const int t  = blockIdx.x;
    const int l  = threadIdx.x;
    const int ks = l >> 1;
    int nz = 0, zany = 0;
    #pragma unroll
    for (int gh = 0; gh < 2; ++gh) {
        const int g = (l & 1) * 2 + gh;
        bf16x8 a8, u8;
        #pragma unroll
        for (int j = 0; j < 8; ++j) {
            const int d  = ks * 32 + g * 8 + j;
            const float b  = base[d];
            const float dl = (t > 0) ? deltas[(size_t)(t - 1) * DIMS + d] : 0.f;
            const float s  = (dl != 0.f) ? dl : b;
            a8[j] = sgnbf(s);
            u8[j] = absbf(s);
            nz   += (s != 0.f) ? 1 : 0;
            zany |= (s == 0.f) ? 1 : 0;
        }
        const int L    = g * 16 + (t & 15);
        const int n    = t >> 4;
        const int slot = n ^ (t & 15);
        const size_t off = (size_t)L * 128 + slot * 8;
        *(bf16x8*)(Bf + (((size_t)0 * 32 + ks) << 13) + off) = a8;
        *(bf16x8*)(Bf + (((size_t)1 * 32 + ks) << 13) + off) = u8;
    }
    #pragma unroll
    for (int off = 1; off < 64; off <<= 1) nz += __shfl_xor(nz, off);
    const bool za = __any(zany != 0);
    if (l == 0) { Sv[t] = (float)nz; flags[t] = za ? 1 : 0; }
}

// ---------------------------------------------------------------------------
// Kernel B: MFMA dist. 256 thr = 4 waves; block = 64 tokens (16/wave, R13's
// bit-exact geometry: acc[16] = 64 AGPR) x 256 tiles. Per ks: B slice staged
// via global_load_lds DMA into 2x16KB double buffer, x prefetched 1 ahead,
// 16 ds_read_b128 + 16 MFMA (setprio-wrapped).
// R15 lesson: do NOT cap regs below acc size — (256,3) at 32 tok/wave
// spilled accumulators (WRITE 1.3GB scratch). At 16 tok/wave total regs
// ~119 -> 4 blocks/CU NATURALLY (16 waves/CU, 128KB LDS): barrier drains
// in one block overlap with 3 others' compute.
// Slow path (sig has exact zero, ~never): second plane pass, same acc.
// ---------------------------------------------------------------------------
__global__ __launch_bounds__(256, 4)
void dist_kernel(const float* __restrict__ x,
                 const short* __restrict__ Bf,
                 const float* __restrict__ Sv,
                 const int* __restrict__ flags,
                 float* __restrict__ idx_out,
                 float* __restrict__ dist_out)
{
    __shared__ short lds[2][8192];   // 32 KB: [buf][16KB slice]

    const int lane = threadIdx.x & 63;
    const int w    = threadIdx.x >> 6;
    const int tok0 = blockIdx.x * 64 + w * 16;
    const int mrow = lane & 15;
    const int g    = lane >> 4;

    const int ff = flags[lane] | flags[64 + lane] | flags[128 + lane] | flags[192 + lane];
    const bool sigz = __any(ff != 0);

    const float* __restrict__ xrow = x + (size_t)(tok0 + mrow) * DIMS + g * 8;

    f32x4 acc[16];
    #pragma unroll
    for (int n = 0; n < 16; ++n) acc[n] = (f32x4){0.f, 0.f, 0.f, 0.f};

    // async DMA stage: wave w copies its 4KB quarter of slice (p,ks)
    auto STAGE = [&](int b, int p, int kss) {
        const short* src = Bf + (((size_t)p * 32 + kss) << 13) + w * 2048 + lane * 8;
        short* dst = &lds[b][w * 2048];
        #pragma unroll
        for (int i = 0; i < 4; ++i) {
            __builtin_amdgcn_global_load_lds(
                (const __attribute__((address_space(1))) u32*)(src + i * 512),
                (__attribute__((address_space(3))) u32*)(dst + i * 512),
                16, 0, 0);
        }
    };

    int nz0 = 0;
    const int nplanes = sigz ? 2 : 1;

    for (int p = 0; p < nplanes; ++p) {
        STAGE(0, p, 0);
        float4 xv0 = *(const float4*)(xrow);
        float4 xv1 = *(const float4*)(xrow + 4);

        for (int ks = 0; ks < 32; ++ks) {
            __syncthreads();   // slice (p,ks) DMA + x(ks) loads complete

            float4 nx0, nx1;
            if (ks < 31) {
                STAGE((ks + 1) & 1, p, ks + 1);
                nx0 = *(const float4*)(xrow + (ks + 1) * 32);
                nx1 = *(const float4*)(xrow + (ks + 1) * 32 + 4);
            }

            bf16x8 f0;
            if (p == 0) {
                f0[0]=sgnbf(xv0.x); f0[1]=sgnbf(xv0.y); f0[2]=sgnbf(xv0.z); f0[3]=sgnbf(xv0.w);
                f0[4]=sgnbf(xv1.x); f0[5]=sgnbf(xv1.y); f0[6]=sgnbf(xv1.z); f0[7]=sgnbf(xv1.w);
            } else {
                f0[0]=absbf(xv0.x); f0[1]=absbf(xv0.y); f0[2]=absbf(xv0.z); f0[3]=absbf(xv0.w);
                f0[4]=absbf(xv1.x); f0[5]=absbf(xv1.y); f0[6]=absbf(xv1.z); f0[7]=absbf(xv1.w);
                nz0 += (xv0.x!=0.f)+(xv0.y!=0.f)+(xv0.z!=0.f)+(xv0.w!=0.f)
                     + (xv1.x!=0.f)+(xv1.y!=0.f)+(xv1.z!=0.f)+(xv1.w!=0.f);
            }

            const short* sa = &lds[ks & 1][0];
            __builtin_amdgcn_s_setprio(1);
            #pragma unroll
            for (int n = 0; n < 16; ++n) {
                const bf16x8 ba = *(const bf16x8*)(sa + lane * 128 + ((n ^ mrow) & 15) * 8);
                acc[n] = __builtin_amdgcn_mfma_f32_16x16x32_bf16(f0, ba, acc[n], 0, 0, 0);
            }
            __builtin_amdgcn_s_setprio(0);

            xv0 = nx0; xv1 = nx1;
        }
        __syncthreads();   // both buffers drained before next plane restages
    }

    // ---- epilogue (R13-verified geometry) ----
    float sur[4];
    if (sigz) {
        nz0 += __shfl_xor(nz0, 16); nz0 += __shfl_xor(nz0, 32);
        const float s0 = (float)nz0;
        #pragma unroll
        for (int r = 0; r < 4; ++r) sur[r] = __shfl(s0, g * 4 + r);
    }

    int key[4] = {0x7fffffff,0x7fffffff,0x7fffffff,0x7fffffff};
    #pragma unroll
    for (int n = 0; n < 16; ++n) {
        const int tile = n * 16 + mrow;
        const float svv = sigz ? Sv[tile] : 0.f;
        #pragma unroll
        for (int r = 0; r < 4; ++r) {
            const float dv = sigz ? (sur[r] + svv - acc[n][r]) : (1024.f - acc[n][r]);
            dist_out[(size_t)(tok0 + g * 4 + r) * NT + tile] = dv;
            key[r] = min(key[r], ((int)dv << 8) | tile);
        }
    }
    #pragma unroll
    for (int off = 1; off < 16; off <<= 1) {
        #pragma unroll
        for (int r = 0; r < 4; ++r)
            key[r] = min(key[r], __shfl_xor(key[r], off));
    }
    if (mrow == 0) {
        #pragma unroll
        for (int r = 0; r < 4; ++r)
            idx_out[tok0 + g * 4 + r] = (float)(key[r] & 255);
    }
}

extern "C" void kernel_launch(void* const* d_in, const int* in_sizes, int n_in,
                              void* d_out, int out_size, void* d_ws, size_t ws_size,
                              hipStream_t stream)
{
    const float* x      = (const float*)d_in[0];
    const float* base   = (const float*)d_in[1];
    const float* deltas = (const float*)d_in[2];

    short* Bf  = (short*)((char*)d_ws + BF_OFF);
    float* Sv  = (float*)((char*)d_ws + SV_OFF);
    int* flags = (int*)((char*)d_ws + FLAG_OFF);

    float* idx_out  = (float*)d_out;                 // N floats (tile indices)
    float* dist_out = idx_out + NTOK;                // N*T floats

    sig_kernel<<<NT, 64, 0, stream>>>(base, deltas, Bf, Sv, flags);
    dist_kernel<<<NTOK / 64, 256, 0, stream>>>(x, Bf, Sv, flags, idx_out, dist_out);
}

// Round 17
// 189.468 us; speedup vs baseline: 4.7290x; 1.0318x over previous
//
#include <hip/hip_runtime.h>

typedef unsigned int u32;

#define NTOK 131072
#define DIMS 1024
#define NT   256

using bf16x8 = __attribute__((ext_vector_type(8))) short;
using f32x4  = __attribute__((ext_vector_type(4))) float;

// d_ws layout:
//   [0, 1MB)        Bf : bf16[2][32][64][16][8]; slice (p,ks) = 16KB;
//                   within slice: L*128 + slot*8 shorts, slot = n ^ (L&15)
//   [1MB, +1KB)     Sv : float[256]   per-tile nonzero count (slow path)
//   [1MB+1KB, ..)   flags : int[256]  per-tile "sig has exact zero" flag
#define BF_OFF   0
#define SV_OFF   (1 << 20)
#define FLAG_OFF ((1 << 20) + 1024)

// dist = Su + Sv - dot(a,b) - dot(u,v)  [R13-verified, exact]
// if sig has NO exact zeros: dist = 1024 - dot(a,b) exactly (any x).
__device__ __forceinline__ short sgnbf(float v) {
    return v > 0.f ? (short)0x3F80 : (v < 0.f ? (short)0xBF80 : (short)0);
}
__device__ __forceinline__ short absbf(float v) {
    return v != 0.f ? (short)0x3F80 : (short)0;
}

// ---------------------------------------------------------------------------
// Kernel A: B-fragments (bf16 sign/abs planes) in MFMA layout, slot-swizzled.
// (unchanged since R14 — bit-exact verified)
// ---------------------------------------------------------------------------
__global__ void sig_kernel(const float* __restrict__ base,
                           const float* __restrict__ deltas,
                           short* __restrict__ Bf,
                           float* __restrict__ Sv,
                           int* __restrict__ flags)
{
    const int t  = blockIdx.x;
    const int l  = threadIdx.x;
    const int ks = l >> 1;
    int nz = 0, zany = 0;
    #pragma unroll
    for (int gh = 0; gh < 2; ++gh) {
        const int g = (l & 1) * 2 + gh;
        bf16x8 a8, u8;
        #pragma unroll
        for (int j = 0; j < 8; ++j) {
            const int d  = ks * 32 + g * 8 + j;
            const float b  = base[d];
            const float dl = (t > 0) ? deltas[(size_t)(t - 1) * DIMS + d] : 0.f;
            const float s  = (dl != 0.f) ? dl : b;
            a8[j] = sgnbf(s);
            u8[j] = absbf(s);
            nz   += (s != 0.f) ? 1 : 0;
            zany |= (s == 0.f) ? 1 : 0;
        }
        const int L    = g * 16 + (t & 15);
        const int n    = t >> 4;
        const int slot = n ^ (t & 15);
        const size_t off = (size_t)L * 128 + slot * 8;
        *(bf16x8*)(Bf + (((size_t)0 * 32 + ks) << 13) + off) = a8;
        *(bf16x8*)(Bf + (((size_t)1 * 32 + ks) << 13) + off) = u8;
    }
    #pragma unroll
    for (int off = 1; off < 64; off <<= 1) nz += __shfl_xor(nz, off);
    const bool za = __any(zany != 0);
    if (l == 0) { Sv[t] = (float)nz; flags[t] = za ? 1 : 0; }
}

// ---------------------------------------------------------------------------
// Kernel B: MFMA dist. 256 thr = 4 waves; block = 128 tokens (32/wave,
// R14-verified 2-m-frag geometry) x 256 tiles. BK=64: per phase kb, a
// 2-slice (32KB) buffer is staged via global_load_lds DMA while the current
// buffer feeds 32 ds_read_b128 + 64 MFMA per wave (~1500cy) — load
// latencies (~900cy) retire inside the phase, so the closing barrier's
// vmcnt drain is free. 16 barriers total. LDS 64KB -> 2 blocks/CU;
// regs ~220 <= 256 cap of (256,2) — no spill (R15 lesson).
// Slow path (sig has exact zero, ~never): second plane pass, same acc.
// ---------------------------------------------------------------------------
__global__ __launch_bounds__(256, 2)
void dist_kernel(const float* __restrict__ x,
                 const short* __restrict__ Bf,
                 const float* __restrict__ Sv,
                 const int* __restrict__ flags,
                 float* __restrict__ idx_out,
                 float* __restrict__ dist_out)
{
    __shared__ short lds[2][16384];   // 64 KB: [buf][2 slices of 16KB]

    const int lane = threadIdx.x & 63;
    const int w    = threadIdx.x >> 6;
    const int tok0 = blockIdx.x * 128 + w * 32;
    const int mrow = lane & 15;
    const int g    = lane >> 4;

    const int ff = flags[lane] | flags[64 + lane] | flags[128 + lane] | flags[192 + lane];
    const bool sigz = __any(ff != 0);

    const float* __restrict__ xr0 = x + (size_t)(tok0 + mrow) * DIMS + g * 8;
    const float* __restrict__ xr1 = x + (size_t)(tok0 + 16 + mrow) * DIMS + g * 8;

    f32x4 acc0[16], acc1[16];
    #pragma unroll
    for (int n = 0; n < 16; ++n) {
        acc0[n] = (f32x4){0.f, 0.f, 0.f, 0.f};
        acc1[n] = (f32x4){0.f, 0.f, 0.f, 0.f};
    }

    // DMA stage: wave w copies its quarter of both slices of phase kb
    auto STAGE = [&](int b, int p, int kb) {
        #pragma unroll
        for (int s = 0; s < 2; ++s) {
            const short* src = Bf + (((size_t)p * 32 + 2 * kb + s) << 13) + w * 2048 + lane * 8;
            #pragma unroll
            for (int i = 0; i < 4; ++i) {
                __builtin_amdgcn_global_load_lds(
                    (const __attribute__((address_space(1))) u32*)(src + i * 512),
                    (__attribute__((address_space(3))) u32*)(&lds[b][s * 8192 + w * 2048 + i * 512]),
                    16, 0, 0);
            }
        }
    };

    int nz0 = 0, nz1 = 0;
    const int nplanes = sigz ? 2 : 1;

    for (int p = 0; p < nplanes; ++p) {
        STAGE(0, p, 0);
        float4 xv[8];
        xv[0] = *(const float4*)(xr0);       xv[1] = *(const float4*)(xr0 + 4);
        xv[2] = *(const float4*)(xr0 + 32);  xv[3] = *(const float4*)(xr0 + 36);
        xv[4] = *(const float4*)(xr1);       xv[5] = *(const float4*)(xr1 + 4);
        xv[6] = *(const float4*)(xr1 + 32);  xv[7] = *(const float4*)(xr1 + 36);

        for (int kb = 0; kb < 16; ++kb) {
            __syncthreads();   // buffer (p,kb) DMA + x(kb) loads complete

            float4 nx[8];
            if (kb < 15) {
                STAGE((kb + 1) & 1, p, kb + 1);
                const int o = (kb + 1) * 64;
                nx[0] = *(const float4*)(xr0 + o);      nx[1] = *(const float4*)(xr0 + o + 4);
                nx[2] = *(const float4*)(xr0 + o + 32); nx[3] = *(const float4*)(xr0 + o + 36);
                nx[4] = *(const float4*)(xr1 + o);      nx[5] = *(const float4*)(xr1 + o + 4);
                nx[6] = *(const float4*)(xr1 + o + 32); nx[7] = *(const float4*)(xr1 + o + 36);
            }

            if (p == 1) {
                #pragma unroll
                for (int i = 0; i < 4; ++i) {
                    nz0 += (xv[i][0]!=0.f)+(xv[i][1]!=0.f)+(xv[i][2]!=0.f)+(xv[i][3]!=0.f);
                    nz1 += (xv[4+i][0]!=0.f)+(xv[4+i][1]!=0.f)+(xv[4+i][2]!=0.f)+(xv[4+i][3]!=0.f);
                }
            }

            #pragma unroll
            for (int s = 0; s < 2; ++s) {
                const float4 a0 = xv[2 * s], a1 = xv[2 * s + 1];
                const float4 b0 = xv[4 + 2 * s], b1 = xv[4 + 2 * s + 1];
                bf16x8 f0, f1;
                if (p == 0) {
                    f0[0]=sgnbf(a0.x); f0[1]=sgnbf(a0.y); f0[2]=sgnbf(a0.z); f0[3]=sgnbf(a0.w);
                    f0[4]=sgnbf(a1.x); f0[5]=sgnbf(a1.y); f0[6]=sgnbf(a1.z); f0[7]=sgnbf(a1.w);
                    f1[0]=sgnbf(b0.x); f1[1]=sgnbf(b0.y); f1[2]=sgnbf(b0.z); f1[3]=sgnbf(b0.w);
                    f1[4]=sgnbf(b1.x); f1[5]=sgnbf(b1.y); f1[6]=sgnbf(b1.z); f1[7]=sgnbf(b1.w);
                } else {
                    f0[0]=absbf(a0.x); f0[1]=absbf(a0.y); f0[2]=absbf(a0.z); f0[3]=absbf(a0.w);
                    f0[4]=absbf(a1.x); f0[5]=absbf(a1.y); f0[6]=absbf(a1.z); f0[7]=absbf(a1.w);
                    f1[0]=absbf(b0.x); f1[1]=absbf(b0.y); f1[2]=absbf(b0.z); f1[3]=absbf(b0.w);
                    f1[4]=absbf(b1.x); f1[5]=absbf(b1.y); f1[6]=absbf(b1.z); f1[7]=absbf(b1.w);
                }

                const short* sa = &lds[kb & 1][s * 8192];
                __builtin_amdgcn_s_setprio(1);
                #pragma unroll
                for (int n = 0; n < 16; ++n) {
                    const bf16x8 ba = *(const bf16x8*)(sa + lane * 128 + ((n ^ mrow) & 15) * 8);
                    acc0[n] = __builtin_amdgcn_mfma_f32_16x16x32_bf16(f0, ba, acc0[n], 0, 0, 0);
                    acc1[n] = __builtin_amdgcn_mfma_f32_16x16x32_bf16(f1, ba, acc1[n], 0, 0, 0);
                }
                __builtin_amdgcn_s_setprio(0);
            }

            #pragma unroll
            for (int i = 0; i < 8; ++i) xv[i] = nx[i];
        }
        __syncthreads();   // both buffers drained before next plane restages
    }

    // ---- epilogue (R14-verified) ----
    float su0r[4], su1r[4];
    if (sigz) {
        nz0 += __shfl_xor(nz0, 16); nz0 += __shfl_xor(nz0, 32);
        nz1 += __shfl_xor(nz1, 16); nz1 += __shfl_xor(nz1, 32);
        const float s0 = (float)nz0, s1 = (float)nz1;
        #pragma unroll
        for (int r = 0; r < 4; ++r) {
            su0r[r] = __shfl(s0, g * 4 + r);
            su1r[r] = __shfl(s1, g * 4 + r);
        }
    }

    int key0[4] = {0x7fffffff,0x7fffffff,0x7fffffff,0x7fffffff};
    int key1[4] = {0x7fffffff,0x7fffffff,0x7fffffff,0x7fffffff};
    #pragma unroll
    for (int n = 0; n < 16; ++n) {
        const int tile = n * 16 + mrow;
        const float svv = sigz ? Sv[tile] : 0.f;
        #pragma unroll
        for (int r = 0; r < 4; ++r) {
            const float dv0 = sigz ? (su0r[r] + svv - acc0[n][r]) : (1024.f - acc0[n][r]);
            const float dv1 = sigz ? (su1r[r] + svv - acc1[n][r]) : (1024.f - acc1[n][r]);
            dist_out[(size_t)(tok0 + g * 4 + r) * NT + tile]      = dv0;
            dist_out[(size_t)(tok0 + 16 + g * 4 + r) * NT + tile] = dv1;
            key0[r] = min(key0[r], ((int)dv0 << 8) | tile);
            key1[r] = min(key1[r], ((int)dv1 << 8) | tile);
        }
    }
    #pragma unroll
    for (int off = 1; off < 16; off <<= 1) {
        #pragma unroll
        for (int r = 0; r < 4; ++r) {
            key0[r] = min(key0[r], __shfl_xor(key0[r], off));
            key1[r] = min(key1[r], __shfl_xor(key1[r], off));
        }
    }
    if (mrow == 0) {
        #pragma unroll
        for (int r = 0; r < 4; ++r) {
            idx_out[tok0 + g * 4 + r]      = (float)(key0[r] & 255);
            idx_out[tok0 + 16 + g * 4 + r] = (float)(key1[r] & 255);
        }
    }
}

extern "C" void kernel_launch(void* const* d_in, const int* in_sizes, int n_in,
                              void* d_out, int out_size, void* d_ws, size_t ws_size,
                              hipStream_t stream)
{
    const float* x      = (const float*)d_in[0];
    const float* base   = (const float*)d_in[1];
    const float* deltas = (const float*)d_in[2];

    short* Bf  = (short*)((char*)d_ws + BF_OFF);
    float* Sv  = (float*)((char*)d_ws + SV_OFF);
    int* flags = (int*)((char*)d_ws + FLAG_OFF);

    float* idx_out  = (float*)d_out;                 // N floats (tile indices)
    float* dist_out = idx_out + NTOK;                // N*T floats

    sig_kernel<<<NT, 64, 0, stream>>>(base, deltas, Bf, Sv, flags);
    dist_kernel<<<NTOK / 128, 256, 0, stream>>>(x, Bf, Sv, flags, idx_out, dist_out);
}